// Round 7
// baseline (127.638 us; speedup 1.0000x reference)
//
#include <hip/hip_runtime.h>
#include <hip/hip_bf16.h>
#include <math.h>

#define N_NODES 8192
#define IN_DIM  512
#define OUT_DIM 512
#define KN      16
#define CAP     128
#define QPB     8

typedef __attribute__((ext_vector_type(8))) short bf16x8;
typedef __attribute__((ext_vector_type(4))) float f32x4;

__device__ __forceinline__ ushort f2bf(float x) {
  __hip_bfloat16 b = __float2bfloat16(x);
  return *reinterpret_cast<ushort*>(&b);
}
__device__ __forceinline__ float bflo(unsigned u) { return __uint_as_float(u << 16); }
__device__ __forceinline__ float bfhi(unsigned u) { return __uint_as_float(u & 0xffff0000u); }

#define GLOAD_LDS16(gp, lp)                                                     \
  __builtin_amdgcn_global_load_lds((const __attribute__((address_space(1))) void*)(gp), \
                                   (__attribute__((address_space(3))) void*)(lp), 16, 0, 0)

// ---------------- prep: h -> A2 (hi|lo bf16) AND f64 G coords, one h pass ----
__global__ __launch_bounds__(256) void prep_kernel(
    const float* __restrict__ h, const float* __restrict__ Wg,
    ushort* __restrict__ A2,
    double* __restrict__ Gx, double* __restrict__ Gy,
    double* __restrict__ Gz, double* __restrict__ Gsq,
    float4* __restrict__ gpk) {
  const int node = (blockIdx.x * 256 + threadIdx.x) >> 6;
  const int lane = threadIdx.x & 63;
  const int k = lane * 8;
  const float* hr = h + (size_t)node * IN_DIM;

  float4 v0 = *(const float4*)&hr[k];
  float4 v1 = *(const float4*)&hr[k + 4];

  ushort h0 = f2bf(v0.x), h1 = f2bf(v0.y), h2 = f2bf(v0.z), h3 = f2bf(v0.w);
  ushort h4 = f2bf(v1.x), h5 = f2bf(v1.y), h6 = f2bf(v1.z), h7 = f2bf(v1.w);
  ushort4 hiA = make_ushort4(h0, h1, h2, h3);
  ushort4 hiB = make_ushort4(h4, h5, h6, h7);
  ushort4 loA = make_ushort4(f2bf(v0.x - bflo((unsigned)h0)), f2bf(v0.y - bflo((unsigned)h1)),
                             f2bf(v0.z - bflo((unsigned)h2)), f2bf(v0.w - bflo((unsigned)h3)));
  ushort4 loB = make_ushort4(f2bf(v1.x - bflo((unsigned)h4)), f2bf(v1.y - bflo((unsigned)h5)),
                             f2bf(v1.z - bflo((unsigned)h6)), f2bf(v1.w - bflo((unsigned)h7)));
  size_t base = (size_t)node * 1024 + k;
  *(ushort4*)&A2[base]           = hiA;
  *(ushort4*)&A2[base + 4]       = hiB;
  *(ushort4*)&A2[base + 512]     = loA;
  *(ushort4*)&A2[base + 512 + 4] = loB;

  float4 w0a = *(const float4*)&Wg[0 * IN_DIM + k];
  float4 w0b = *(const float4*)&Wg[0 * IN_DIM + k + 4];
  float4 w1a = *(const float4*)&Wg[1 * IN_DIM + k];
  float4 w1b = *(const float4*)&Wg[1 * IN_DIM + k + 4];
  float4 w2a = *(const float4*)&Wg[2 * IN_DIM + k];
  float4 w2b = *(const float4*)&Wg[2 * IN_DIM + k + 4];

  double s0 = 0.0, s1 = 0.0, s2 = 0.0;
  s0 += (double)v0.x * w0a.x; s0 += (double)v0.y * w0a.y;
  s0 += (double)v0.z * w0a.z; s0 += (double)v0.w * w0a.w;
  s0 += (double)v1.x * w0b.x; s0 += (double)v1.y * w0b.y;
  s0 += (double)v1.z * w0b.z; s0 += (double)v1.w * w0b.w;
  s1 += (double)v0.x * w1a.x; s1 += (double)v0.y * w1a.y;
  s1 += (double)v0.z * w1a.z; s1 += (double)v0.w * w1a.w;
  s1 += (double)v1.x * w1b.x; s1 += (double)v1.y * w1b.y;
  s1 += (double)v1.z * w1b.z; s1 += (double)v1.w * w1b.w;
  s2 += (double)v0.x * w2a.x; s2 += (double)v0.y * w2a.y;
  s2 += (double)v0.z * w2a.z; s2 += (double)v0.w * w2a.w;
  s2 += (double)v1.x * w2b.x; s2 += (double)v1.y * w2b.y;
  s2 += (double)v1.z * w2b.z; s2 += (double)v1.w * w2b.w;

  #pragma unroll
  for (int off = 32; off; off >>= 1) {
    s0 += __shfl_down(s0, off);
    s1 += __shfl_down(s1, off);
    s2 += __shfl_down(s2, off);
  }
  if (lane == 0) {
    double sq = s0 * s0 + s1 * s1 + s2 * s2;
    Gx[node] = s0; Gy[node] = s1; Gz[node] = s2; Gsq[node] = sq;
    gpk[node] = make_float4((float)s0, (float)s1, (float)s2, -(float)sq);
  }
}

// ---------------- split W -> Bqk (hi, K'=512) and Bv (hi|hi, K'=1024) ----
__global__ __launch_bounds__(256) void split_w(const float* __restrict__ Wq,
                                               const float* __restrict__ Wk,
                                               const float* __restrict__ Wv,
                                               ushort* __restrict__ Bqk,
                                               ushort* __restrict__ Bv) {
  int i = blockIdx.x * 256 + threadIdx.x;
  int n  = i >> 7;
  int kc = (i & 127) << 2;
  if (n < 1024) {
    const float* W = (n < 512) ? Wq : Wk;
    int r = n & 511;
    float4 v = *(const float4*)&W[(size_t)r * 512 + kc];
    *(ushort4*)&Bqk[(size_t)n * 512 + kc] =
        make_ushort4(f2bf(v.x), f2bf(v.y), f2bf(v.z), f2bf(v.w));
  } else {
    int r = n - 1024;
    float4 v = *(const float4*)&Wv[(size_t)r * 512 + kc];
    ushort4 hv = make_ushort4(f2bf(v.x), f2bf(v.y), f2bf(v.z), f2bf(v.w));
    *(ushort4*)&Bv[(size_t)r * 1024 + kc]       = hv;
    *(ushort4*)&Bv[(size_t)r * 1024 + 512 + kc] = hv;
  }
}

// ---------------- Q/K/V bf16 MFMA GEMM (standalone, QK at K=512) ---------
__global__ __launch_bounds__(256) void gemm_qkv(
    const ushort* __restrict__ A2, const ushort* __restrict__ Bqk,
    const ushort* __restrict__ Bv,
    ushort* __restrict__ Q2, ushort* __restrict__ K2, ushort* __restrict__ V2) {
  __shared__ ushort lA[128 * 32];
  __shared__ ushort lB[128 * 32];
  const int tid = threadIdx.x, w = tid >> 6, lane = tid & 63;
  const int id = blockIdx.x;
  const int sw = (id & 7) * 96 + (id >> 3);   // XCD-contiguous (768%8==0)
  const int bm = sw / 12, bn = sw % 12;
  const int wr = w >> 1, wc = w & 1;
  const bool isv = (bn >= 8);
  const int  kmax = isv ? 1024 : 512;
  const int  ldb  = isv ? 1024 : 512;
  const ushort* Bb = isv ? (Bv + (size_t)(bn - 8) * 128 * 1024)
                         : (Bqk + (size_t)bn * 128 * 512);

  f32x4 acc[4][4] = {};

  const int   srow = w * 32 + (lane >> 2);
  const int   scol = (lane & 3) * 8;
  const size_t gA0 = (size_t)(bm * 128 + srow) * 1024 + scol;
  const size_t gB0 = (size_t)srow * ldb + scol;

  for (int k0 = 0; k0 < kmax; k0 += 32) {
    GLOAD_LDS16(&A2[gA0 + k0],                    &lA[w * 1024]);
    GLOAD_LDS16(&A2[gA0 + 16 * 1024 + k0],        &lA[w * 1024 + 512]);
    GLOAD_LDS16(&Bb[gB0 + k0],                    &lB[w * 1024]);
    GLOAD_LDS16(&Bb[gB0 + (size_t)16 * ldb + k0], &lB[w * 1024 + 512]);
    __syncthreads();

    const int ar = wr * 64 + (lane & 15);
    const int br = wc * 64 + (lane & 15);
    const int kc = (lane >> 4) * 8;
    bf16x8 af[4], bfr[4];
    #pragma unroll
    for (int f = 0; f < 4; ++f) {
      af[f]  = *(const bf16x8*)&lA[(ar + f * 16) * 32 + kc];
      bfr[f] = *(const bf16x8*)&lB[(br + f * 16) * 32 + kc];
    }
    #pragma unroll
    for (int fm = 0; fm < 4; ++fm)
      #pragma unroll
      for (int fn = 0; fn < 4; ++fn)
        acc[fm][fn] = __builtin_amdgcn_mfma_f32_16x16x32_bf16(af[fm], bfr[fn], acc[fm][fn], 0, 0, 0);
    __syncthreads();
  }

  ushort* Cm = isv ? V2 : (bn < 4 ? Q2 : K2);
  const int col  = (isv ? (bn - 8) : (bn & 3)) * 128 + wc * 64 + (lane & 15);
  const int row0 = bm * 128 + wr * 64 + (lane >> 4) * 4;
  #pragma unroll
  for (int fm = 0; fm < 4; ++fm)
    #pragma unroll
    for (int fn = 0; fn < 4; ++fn)
      #pragma unroll
      for (int r = 0; r < 4; ++r)
        Cm[(size_t)(row0 + fm * 16 + r) * 512 + col + fn * 16] = f2bf(acc[fm][fn][r]);
}

// ---------------- fused knn + attend: 8 dst nodes per block --------------
#define SM_BYTES 20544

__global__ __launch_bounds__(256) void knn_attend(
    const float4* __restrict__ gpk,
    const double* __restrict__ Gx, const double* __restrict__ Gy,
    const double* __restrict__ Gz, const double* __restrict__ Gsq,
    const ushort* __restrict__ Q2, const ushort* __restrict__ K2,
    const ushort* __restrict__ V2, float* __restrict__ out) {
  __shared__ unsigned long long smraw[SM_BYTES / 8];
  const int tid = threadIdx.x, w = tid >> 6, lane = tid & 63;
  const int qbase = blockIdx.x * QPB;

  // overlays: [0,8192) = s_tmax during A/B, then attend tables after C
  float (*s_tmax)[256] = (float(*)[256])smraw;
  int   (*s_nidx)[KN]  = (int(*)[KN])smraw;                       // 512 B
  float (*s_d2f)[KN]   = (float(*)[KN])((char*)smraw + 512);      // 512 B
  float (*s_sc)[KN]    = (float(*)[KN])((char*)smraw + 1024);     // 512 B
  float (*s_wv)[KN]    = (float(*)[KN])((char*)smraw + 1536);     // 512 B
  int   (*s_cand)[CAP] = (int(*)[CAP])((char*)smraw + 8192);      // 4 KB
  double(*s_dval)[CAP] = (double(*)[CAP])((char*)smraw + 12288);  // 8 KB
  int*   s_cnt = (int*)((char*)smraw + 20480);
  float* s_T   = (float*)((char*)smraw + 20512);

  float q2x[QPB], q2y[QPB], q2z[QPB], tmax[QPB];
  #pragma unroll
  for (int s = 0; s < QPB; ++s) {
    float4 qv = gpk[qbase + s];
    q2x[s] = 2.f * qv.x; q2y[s] = 2.f * qv.y; q2z[s] = 2.f * qv.z;
    tmax[s] = -1e30f;
  }
  if (tid < QPB) s_cnt[tid] = 0;

  // Phase A: branchless max scan with register prefetch
  {
    float4 c0 = gpk[tid];
    float4 c1 = gpk[tid + 256];
    for (int i = 0; i < 16; ++i) {
      int nx = ((i + 1) & 15) * 512;
      float4 n0 = gpk[tid + nx];
      float4 n1 = gpk[tid + nx + 256];
      #pragma unroll
      for (int s = 0; s < QPB; ++s) {
        float v0 = fmaf(q2x[s], c0.x, fmaf(q2y[s], c0.y, fmaf(q2z[s], c0.z, c0.w)));
        float v1 = fmaf(q2x[s], c1.x, fmaf(q2y[s], c1.y, fmaf(q2z[s], c1.z, c1.w)));
        tmax[s] = fmaxf(fmaxf(tmax[s], v0), v1);
      }
      c0 = n0; c1 = n1;
    }
  }
  #pragma unroll
  for (int s = 0; s < QPB; ++s) s_tmax[s][tid] = tmax[s];
  __syncthreads();

  // Phase B: exact 16th-of-64 via radix select on monotone float->uint map
  #pragma unroll
  for (int qq = 0; qq < 2; ++qq) {
    int q = w * 2 + qq;
    float v = fmaxf(fmaxf(s_tmax[q][lane], s_tmax[q][lane + 64]),
                    fmaxf(s_tmax[q][lane + 128], s_tmax[q][lane + 192]));
    unsigned b = __float_as_uint(v);
    unsigned u = b ^ ((unsigned)((int)b >> 31) | 0x80000000u);
    unsigned thr = 0;
    for (int bit = 31; bit >= 0; --bit) {
      unsigned cand = thr | (1u << bit);
      unsigned long long m = __ballot(u >= cand);
      if (__popcll(m) >= KN) thr = cand;
    }
    unsigned tb = (thr & 0x80000000u) ? (thr ^ 0x80000000u) : ~thr;
    if (lane == 0) s_T[q] = __uint_as_float(tb);
  }
  __syncthreads();

  // Phase C: rescan (identical FMA chain), collect candidates >= T
  float Ts[QPB];
  #pragma unroll
  for (int s = 0; s < QPB; ++s) Ts[s] = s_T[s];
  {
    float4 c0 = gpk[tid];
    float4 c1 = gpk[tid + 256];
    for (int i = 0; i < 16; ++i) {
      int nx = ((i + 1) & 15) * 512;
      float4 n0 = gpk[tid + nx];
      float4 n1 = gpk[tid + nx + 256];
      int j0 = tid + i * 512, j1 = j0 + 256;
      #pragma unroll
      for (int s = 0; s < QPB; ++s) {
        float v0 = fmaf(q2x[s], c0.x, fmaf(q2y[s], c0.y, fmaf(q2z[s], c0.z, c0.w)));
        float v1 = fmaf(q2x[s], c1.x, fmaf(q2y[s], c1.y, fmaf(q2z[s], c1.z, c1.w)));
        if (v0 >= Ts[s]) { int p = atomicAdd(&s_cnt[s], 1); if (p < CAP) s_cand[s][p] = j0; }
        if (v1 >= Ts[s]) { int p = atomicAdd(&s_cnt[s], 1); if (p < CAP) s_cand[s][p] = j1; }
      }
      c0 = n0; c1 = n1;
    }
  }
  __syncthreads();

  // Phase D: exact f64 scores, rank-by-counting -> per-query top-16 in LDS
  const int qA = w * 2, qB = qA + 1;
  const int cntA = min(s_cnt[qA], CAP);
  const int cntB = min(s_cnt[qB], CAP);
  int j0a = -1, j1a = -1, j0b = -1, j1b = -1;
  double v0a = 0, v1a = 0, v0b = 0, v1b = 0;
  {
    int gq = qbase + qA;
    double xi = Gx[gq], yi = Gy[gq], zi = Gz[gq], sqi = Gsq[gq];
    if (lane < cntA) {
      j0a = s_cand[qA][lane];
      v0a = 2.0 * (xi * Gx[j0a] + yi * Gy[j0a] + zi * Gz[j0a]) - sqi - Gsq[j0a];
      s_dval[qA][lane] = v0a;
    }
    if (lane + 64 < cntA) {
      j1a = s_cand[qA][lane + 64];
      v1a = 2.0 * (xi * Gx[j1a] + yi * Gy[j1a] + zi * Gz[j1a]) - sqi - Gsq[j1a];
      s_dval[qA][lane + 64] = v1a;
    }
  }
  {
    int gq = qbase + qB;
    double xi = Gx[gq], yi = Gy[gq], zi = Gz[gq], sqi = Gsq[gq];
    if (lane < cntB) {
      j0b = s_cand[qB][lane];
      v0b = 2.0 * (xi * Gx[j0b] + yi * Gy[j0b] + zi * Gz[j0b]) - sqi - Gsq[j0b];
      s_dval[qB][lane] = v0b;
    }
    if (lane + 64 < cntB) {
      j1b = s_cand[qB][lane + 64];
      v1b = 2.0 * (xi * Gx[j1b] + yi * Gy[j1b] + zi * Gz[j1b]) - sqi - Gsq[j1b];
      s_dval[qB][lane + 64] = v1b;
    }
  }
  __syncthreads();
  {
    int r0 = 0, r1 = 0;
    for (int m = 0; m < cntA; ++m) {
      double dv = s_dval[qA][m]; int di = s_cand[qA][m];
      r0 += (dv > v0a) || (dv == v0a && di < j0a);
      r1 += (dv > v1a) || (dv == v1a && di < j1a);
    }
    if (j0a >= 0 && r0 < KN) { s_nidx[qA][r0] = j0a; s_d2f[qA][r0] = fmaxf(-(float)v0a, 0.f); }
    if (j1a >= 0 && r1 < KN) { s_nidx[qA][r1] = j1a; s_d2f[qA][r1] = fmaxf(-(float)v1a, 0.f); }
    int r2 = 0, r3 = 0;
    for (int m = 0; m < cntB; ++m) {
      double dv = s_dval[qB][m]; int di = s_cand[qB][m];
      r2 += (dv > v0b) || (dv == v0b && di < j0b);
      r3 += (dv > v1b) || (dv == v1b && di < j1b);
    }
    if (j0b >= 0 && r2 < KN) { s_nidx[qB][r2] = j0b; s_d2f[qB][r2] = fmaxf(-(float)v0b, 0.f); }
    if (j1b >= 0 && r3 < KN) { s_nidx[qB][r3] = j1b; s_d2f[qB][r3] = fmaxf(-(float)v1b, 0.f); }
  }
  __syncthreads();

  // Attend phase: wave w owns queries 2w, 2w+1
  const int g = lane >> 2, c = lane & 3;
  #pragma unroll
  for (int qq = 0; qq < 2; ++qq) {
    const int q = w * 2 + qq;
    const int qnode = qbase + q;

    // QK: group g (4 lanes) computes neighbor g's dot over 512 dims
    int nb = s_nidx[q][g];
    const ushort* Qr = Q2 + (size_t)qnode * 512 + c * 128;
    const ushort* Kr = K2 + (size_t)nb * 512 + c * 128;
    float acc = 0.f;
    #pragma unroll
    for (int t = 0; t < 16; ++t) {
      uint4 qa = *(const uint4*)&Qr[t * 8];
      uint4 ka = *(const uint4*)&Kr[t * 8];
      acc = fmaf(bflo(qa.x), bflo(ka.x), acc);
      acc = fmaf(bfhi(qa.x), bfhi(ka.x), acc);
      acc = fmaf(bflo(qa.y), bflo(ka.y), acc);
      acc = fmaf(bfhi(qa.y), bfhi(ka.y), acc);
      acc = fmaf(bflo(qa.z), bflo(ka.z), acc);
      acc = fmaf(bfhi(qa.z), bfhi(ka.z), acc);
      acc = fmaf(bflo(qa.w), bflo(ka.w), acc);
      acc = fmaf(bfhi(qa.w), bfhi(ka.w), acc);
    }
    acc += __shfl_xor(acc, 1);
    acc += __shfl_xor(acc, 2);
    if (c == 0) s_sc[q][g] = acc;

    // weights: e = lane&15 (4x redundant across the wave)
    int e = lane & 15;
    float sc = s_sc[q][e] * (1.f / 22.627417f);
    sc = fminf(fmaxf(sc, -5.f), 5.f);
    float se = expf(sc);
    float d2 = s_d2f[q][e];
    float dd = -sqrtf(d2 + 1e-6f);
    float dc = fminf(fmaxf(dd * (1.f / 22.627417f), -5.f), 5.f);
    float de = expf(dc);
    if (lane < 16) s_wv[q][e] = se * de;
    float zz = se;
    #pragma unroll
    for (int off = 32; off; off >>= 1) zz += __shfl_xor(zz, off);
    float z = zz * 0.25f;   // each se counted 4x

    // V accumulation: lane owns dims [lane*8, lane*8+8)
    const int d0 = lane * 8;
    float o0 = 0.f, o1 = 0.f, o2 = 0.f, o3 = 0.f, o4 = 0.f, o5 = 0.f, o6 = 0.f, o7 = 0.f;
    #pragma unroll
    for (int e2 = 0; e2 < KN; ++e2) {
      int nb2 = s_nidx[q][e2];
      float wgt = s_wv[q][e2];
      uint4 va = *(const uint4*)&V2[(size_t)nb2 * 512 + d0];
      o0 = fmaf(wgt, bflo(va.x), o0);
      o1 = fmaf(wgt, bfhi(va.x), o1);
      o2 = fmaf(wgt, bflo(va.y), o2);
      o3 = fmaf(wgt, bfhi(va.y), o3);
      o4 = fmaf(wgt, bflo(va.z), o4);
      o5 = fmaf(wgt, bfhi(va.z), o5);
      o6 = fmaf(wgt, bflo(va.w), o6);
      o7 = fmaf(wgt, bfhi(va.w), o7);
    }
    float inv = (z > 0.f) ? (1.f / z) : 1.f;
    float4 w0 = {o0 * inv, o1 * inv, o2 * inv, o3 * inv};
    float4 w1 = {o4 * inv, o5 * inv, o6 * inv, o7 * inv};
    *(float4*)&out[(size_t)qnode * 512 + d0]     = w0;
    *(float4*)&out[(size_t)qnode * 512 + d0 + 4] = w1;
  }
}

extern "C" void kernel_launch(void* const* d_in, const int* in_sizes, int n_in,
                              void* d_out, int out_size, void* d_ws, size_t ws_size,
                              hipStream_t stream) {
  const float* h  = (const float*)d_in[0];
  const float* Wq = (const float*)d_in[1];
  const float* Wk = (const float*)d_in[2];
  const float* Wv = (const float*)d_in[3];
  const float* Wg = (const float*)d_in[4];
  float* out = (float*)d_out;

  char* ws = (char*)d_ws;
  ushort* A2  = (ushort*)(ws);                 // 16 MB
  ushort* Bqk = (ushort*)(ws + (16u << 20));   // 1 MB
  ushort* Bv  = (ushort*)(ws + (17u << 20));   // 1 MB
  ushort* Q2  = (ushort*)(ws + (18u << 20));   // 8 MB
  ushort* K2  = (ushort*)(ws + (26u << 20));   // 8 MB
  ushort* V2  = (ushort*)(ws + (34u << 20));   // 8 MB
  float4* gpk = (float4*)(ws + (42u << 20));   // 128 KB
  double* Gx  = (double*)(ws + (42u << 20) + (1u << 17));
  double* Gy  = Gx + N_NODES;
  double* Gz  = Gy + N_NODES;
  double* Gsq = Gz + N_NODES;

  hipLaunchKernelGGL(prep_kernel, dim3(N_NODES / 4), dim3(256), 0, stream,
                     h, Wg, A2, Gx, Gy, Gz, Gsq, gpk);
  hipLaunchKernelGGL(split_w, dim3(768), dim3(256), 0, stream,
                     Wq, Wk, Wv, Bqk, Bv);
  hipLaunchKernelGGL(gemm_qkv, dim3(768), dim3(256), 0, stream,
                     A2, Bqk, Bv, Q2, K2, V2);
  hipLaunchKernelGGL(knn_attend, dim3(N_NODES / QPB), dim3(256), 0, stream,
                     gpk, Gx, Gy, Gz, Gsq, Q2, K2, V2, out);
}

// Round 8
// 103.550 us; speedup vs baseline: 1.2326x; 1.2326x over previous
//
#include <hip/hip_runtime.h>
#include <hip/hip_bf16.h>
#include <math.h>

#define N_NODES 8192
#define IN_DIM  512
#define OUT_DIM 512
#define KN      16
#define CAP     128
#define QPB     8

typedef __attribute__((ext_vector_type(8))) short bf16x8;
typedef __attribute__((ext_vector_type(4))) float f32x4;

__device__ __forceinline__ ushort f2bf(float x) {
  __hip_bfloat16 b = __float2bfloat16(x);
  return *reinterpret_cast<ushort*>(&b);
}
__device__ __forceinline__ float bflo(unsigned u) { return __uint_as_float(u << 16); }
__device__ __forceinline__ float bfhi(unsigned u) { return __uint_as_float(u & 0xffff0000u); }

#define GLOAD_LDS16(gp, lp)                                                     \
  __builtin_amdgcn_global_load_lds((const __attribute__((address_space(1))) void*)(gp), \
                                   (__attribute__((address_space(3))) void*)(lp), 16, 0, 0)

// ------- fused prep: blocks <2048 do h->A2 + f64 G; blocks >=2048 split W ----
__global__ __launch_bounds__(256) void prep_split(
    const float* __restrict__ h, const float* __restrict__ Wg,
    const float* __restrict__ Wq, const float* __restrict__ Wk,
    const float* __restrict__ Wv,
    ushort* __restrict__ A2, ushort* __restrict__ Bqk, ushort* __restrict__ Bv,
    double* __restrict__ Gx, double* __restrict__ Gy,
    double* __restrict__ Gz, double* __restrict__ Gsq,
    float4* __restrict__ gpk) {
  if (blockIdx.x < 2048) {
    const int node = (blockIdx.x * 256 + threadIdx.x) >> 6;
    const int lane = threadIdx.x & 63;
    const int k = lane * 8;
    const float* hr = h + (size_t)node * IN_DIM;

    float4 v0 = *(const float4*)&hr[k];
    float4 v1 = *(const float4*)&hr[k + 4];

    ushort h0 = f2bf(v0.x), h1 = f2bf(v0.y), h2 = f2bf(v0.z), h3 = f2bf(v0.w);
    ushort h4 = f2bf(v1.x), h5 = f2bf(v1.y), h6 = f2bf(v1.z), h7 = f2bf(v1.w);
    ushort4 hiA = make_ushort4(h0, h1, h2, h3);
    ushort4 hiB = make_ushort4(h4, h5, h6, h7);
    ushort4 loA = make_ushort4(f2bf(v0.x - bflo((unsigned)h0)), f2bf(v0.y - bflo((unsigned)h1)),
                               f2bf(v0.z - bflo((unsigned)h2)), f2bf(v0.w - bflo((unsigned)h3)));
    ushort4 loB = make_ushort4(f2bf(v1.x - bflo((unsigned)h4)), f2bf(v1.y - bflo((unsigned)h5)),
                               f2bf(v1.z - bflo((unsigned)h6)), f2bf(v1.w - bflo((unsigned)h7)));
    size_t base = (size_t)node * 1024 + k;
    *(ushort4*)&A2[base]           = hiA;
    *(ushort4*)&A2[base + 4]       = hiB;
    *(ushort4*)&A2[base + 512]     = loA;
    *(ushort4*)&A2[base + 512 + 4] = loB;

    float4 w0a = *(const float4*)&Wg[0 * IN_DIM + k];
    float4 w0b = *(const float4*)&Wg[0 * IN_DIM + k + 4];
    float4 w1a = *(const float4*)&Wg[1 * IN_DIM + k];
    float4 w1b = *(const float4*)&Wg[1 * IN_DIM + k + 4];
    float4 w2a = *(const float4*)&Wg[2 * IN_DIM + k];
    float4 w2b = *(const float4*)&Wg[2 * IN_DIM + k + 4];

    double s0 = 0.0, s1 = 0.0, s2 = 0.0;
    s0 += (double)v0.x * w0a.x; s0 += (double)v0.y * w0a.y;
    s0 += (double)v0.z * w0a.z; s0 += (double)v0.w * w0a.w;
    s0 += (double)v1.x * w0b.x; s0 += (double)v1.y * w0b.y;
    s0 += (double)v1.z * w0b.z; s0 += (double)v1.w * w0b.w;
    s1 += (double)v0.x * w1a.x; s1 += (double)v0.y * w1a.y;
    s1 += (double)v0.z * w1a.z; s1 += (double)v0.w * w1a.w;
    s1 += (double)v1.x * w1b.x; s1 += (double)v1.y * w1b.y;
    s1 += (double)v1.z * w1b.z; s1 += (double)v1.w * w1b.w;
    s2 += (double)v0.x * w2a.x; s2 += (double)v0.y * w2a.y;
    s2 += (double)v0.z * w2a.z; s2 += (double)v0.w * w2a.w;
    s2 += (double)v1.x * w2b.x; s2 += (double)v1.y * w2b.y;
    s2 += (double)v1.z * w2b.z; s2 += (double)v1.w * w2b.w;

    #pragma unroll
    for (int off = 32; off; off >>= 1) {
      s0 += __shfl_down(s0, off);
      s1 += __shfl_down(s1, off);
      s2 += __shfl_down(s2, off);
    }
    if (lane == 0) {
      double sq = s0 * s0 + s1 * s1 + s2 * s2;
      Gx[node] = s0; Gy[node] = s1; Gz[node] = s2; Gsq[node] = sq;
      gpk[node] = make_float4((float)s0, (float)s1, (float)s2, -(float)sq);
    }
  } else {
    int i = (blockIdx.x - 2048) * 256 + threadIdx.x;
    int n  = i >> 7;
    int kc = (i & 127) << 2;
    if (n < 1024) {
      const float* W = (n < 512) ? Wq : Wk;
      int r = n & 511;
      float4 v = *(const float4*)&W[(size_t)r * 512 + kc];
      *(ushort4*)&Bqk[(size_t)n * 512 + kc] =
          make_ushort4(f2bf(v.x), f2bf(v.y), f2bf(v.z), f2bf(v.w));
    } else {
      int r = n - 1024;
      float4 v = *(const float4*)&Wv[(size_t)r * 512 + kc];
      ushort4 hv = make_ushort4(f2bf(v.x), f2bf(v.y), f2bf(v.z), f2bf(v.w));
      *(ushort4*)&Bv[(size_t)r * 1024 + kc]       = hv;
      *(ushort4*)&Bv[(size_t)r * 1024 + 512 + kc] = hv;
    }
  }
}

// ---------------- Q/K/V bf16 MFMA GEMM (QK at K=512, V at K=1024) --------
__global__ __launch_bounds__(256) void gemm_qkv(
    const ushort* __restrict__ A2, const ushort* __restrict__ Bqk,
    const ushort* __restrict__ Bv,
    ushort* __restrict__ Q2, ushort* __restrict__ K2, ushort* __restrict__ V2) {
  __shared__ ushort lA[128 * 32];
  __shared__ ushort lB[128 * 32];
  const int tid = threadIdx.x, w = tid >> 6, lane = tid & 63;
  const int id = blockIdx.x;
  const int sw = (id & 7) * 96 + (id >> 3);   // XCD-contiguous (768%8==0)
  const int bm = sw / 12, bn = sw % 12;
  const int wr = w >> 1, wc = w & 1;
  const bool isv = (bn >= 8);
  const int  kmax = isv ? 1024 : 512;
  const int  ldb  = isv ? 1024 : 512;
  const ushort* Bb = isv ? (Bv + (size_t)(bn - 8) * 128 * 1024)
                         : (Bqk + (size_t)bn * 128 * 512);

  f32x4 acc[4][4] = {};

  const int   srow = w * 32 + (lane >> 2);
  const int   scol = (lane & 3) * 8;
  const size_t gA0 = (size_t)(bm * 128 + srow) * 1024 + scol;
  const size_t gB0 = (size_t)srow * ldb + scol;

  for (int k0 = 0; k0 < kmax; k0 += 32) {
    GLOAD_LDS16(&A2[gA0 + k0],                    &lA[w * 1024]);
    GLOAD_LDS16(&A2[gA0 + 16 * 1024 + k0],        &lA[w * 1024 + 512]);
    GLOAD_LDS16(&Bb[gB0 + k0],                    &lB[w * 1024]);
    GLOAD_LDS16(&Bb[gB0 + (size_t)16 * ldb + k0], &lB[w * 1024 + 512]);
    __syncthreads();

    const int ar = wr * 64 + (lane & 15);
    const int br = wc * 64 + (lane & 15);
    const int kc = (lane >> 4) * 8;
    bf16x8 af[4], bfr[4];
    #pragma unroll
    for (int f = 0; f < 4; ++f) {
      af[f]  = *(const bf16x8*)&lA[(ar + f * 16) * 32 + kc];
      bfr[f] = *(const bf16x8*)&lB[(br + f * 16) * 32 + kc];
    }
    #pragma unroll
    for (int fm = 0; fm < 4; ++fm)
      #pragma unroll
      for (int fn = 0; fn < 4; ++fn)
        acc[fm][fn] = __builtin_amdgcn_mfma_f32_16x16x32_bf16(af[fm], bfr[fn], acc[fm][fn], 0, 0, 0);
    __syncthreads();
  }

  ushort* Cm = isv ? V2 : (bn < 4 ? Q2 : K2);
  const int col  = (isv ? (bn - 8) : (bn & 3)) * 128 + wc * 64 + (lane & 15);
  const int row0 = bm * 128 + wr * 64 + (lane >> 4) * 4;
  #pragma unroll
  for (int fm = 0; fm < 4; ++fm)
    #pragma unroll
    for (int fn = 0; fn < 4; ++fn)
      #pragma unroll
      for (int r = 0; r < 4; ++r)
        Cm[(size_t)(row0 + fm * 16 + r) * 512 + col + fn * 16] = f2bf(acc[fm][fn][r]);
}

// ---------------- knn: 8 queries/block, radix-select threshold -----------
__global__ __launch_bounds__(256) void knn_kernel(
    const float4* __restrict__ gpk,
    const double* __restrict__ Gx, const double* __restrict__ Gy,
    const double* __restrict__ Gz, const double* __restrict__ Gsq,
    int* __restrict__ knn) {
  const int tid   = threadIdx.x;
  const int w     = tid >> 6;
  const int lane  = tid & 63;
  const int qbase = blockIdx.x * QPB;

  __shared__ float  s_tmax[QPB][256];
  __shared__ int    s_cand[QPB][CAP];
  __shared__ double s_dval[QPB][CAP];
  __shared__ int    s_cnt[QPB];
  __shared__ float  s_T[QPB];

  float q2x[QPB], q2y[QPB], q2z[QPB], tmax[QPB];
  #pragma unroll
  for (int s = 0; s < QPB; ++s) {
    float4 qv = gpk[qbase + s];
    q2x[s] = 2.f * qv.x; q2y[s] = 2.f * qv.y; q2z[s] = 2.f * qv.z;
    tmax[s] = -1e30f;
  }
  if (tid < QPB) s_cnt[tid] = 0;

  // Phase A: branchless max scan with register prefetch
  {
    float4 c0 = gpk[tid];
    float4 c1 = gpk[tid + 256];
    for (int i = 0; i < 16; ++i) {
      int nx = ((i + 1) & 15) * 512;
      float4 n0 = gpk[tid + nx];
      float4 n1 = gpk[tid + nx + 256];
      #pragma unroll
      for (int s = 0; s < QPB; ++s) {
        float v0 = fmaf(q2x[s], c0.x, fmaf(q2y[s], c0.y, fmaf(q2z[s], c0.z, c0.w)));
        float v1 = fmaf(q2x[s], c1.x, fmaf(q2y[s], c1.y, fmaf(q2z[s], c1.z, c1.w)));
        tmax[s] = fmaxf(fmaxf(tmax[s], v0), v1);
      }
      c0 = n0; c1 = n1;
    }
  }
  #pragma unroll
  for (int s = 0; s < QPB; ++s) s_tmax[s][tid] = tmax[s];
  __syncthreads();

  // Phase B: exact 16th-of-64 via radix select on monotone float->uint map
  #pragma unroll
  for (int qq = 0; qq < 2; ++qq) {
    int q = w * 2 + qq;
    float v = fmaxf(fmaxf(s_tmax[q][lane], s_tmax[q][lane + 64]),
                    fmaxf(s_tmax[q][lane + 128], s_tmax[q][lane + 192]));
    unsigned b = __float_as_uint(v);
    unsigned u = b ^ ((unsigned)((int)b >> 31) | 0x80000000u);
    unsigned thr = 0;
    for (int bit = 31; bit >= 0; --bit) {
      unsigned cand = thr | (1u << bit);
      unsigned long long m = __ballot(u >= cand);
      if (__popcll(m) >= KN) thr = cand;
    }
    unsigned tb = (thr & 0x80000000u) ? (thr ^ 0x80000000u) : ~thr;
    if (lane == 0) s_T[q] = __uint_as_float(tb);
  }
  __syncthreads();

  // Phase C: rescan (identical FMA chain), collect candidates >= T
  float Ts[QPB];
  #pragma unroll
  for (int s = 0; s < QPB; ++s) Ts[s] = s_T[s];
  {
    float4 c0 = gpk[tid];
    float4 c1 = gpk[tid + 256];
    for (int i = 0; i < 16; ++i) {
      int nx = ((i + 1) & 15) * 512;
      float4 n0 = gpk[tid + nx];
      float4 n1 = gpk[tid + nx + 256];
      int j0 = tid + i * 512, j1 = j0 + 256;
      #pragma unroll
      for (int s = 0; s < QPB; ++s) {
        float v0 = fmaf(q2x[s], c0.x, fmaf(q2y[s], c0.y, fmaf(q2z[s], c0.z, c0.w)));
        float v1 = fmaf(q2x[s], c1.x, fmaf(q2y[s], c1.y, fmaf(q2z[s], c1.z, c1.w)));
        if (v0 >= Ts[s]) { int p = atomicAdd(&s_cnt[s], 1); if (p < CAP) s_cand[s][p] = j0; }
        if (v1 >= Ts[s]) { int p = atomicAdd(&s_cnt[s], 1); if (p < CAP) s_cand[s][p] = j1; }
      }
      c0 = n0; c1 = n1;
    }
  }
  __syncthreads();

  // Phase D: exact f64 scores, rank-by-counting
  const int qA = w * 2, qB = qA + 1;
  const int cntA = min(s_cnt[qA], CAP);
  const int cntB = min(s_cnt[qB], CAP);
  int j0a = -1, j1a = -1, j0b = -1, j1b = -1;
  double v0a = 0, v1a = 0, v0b = 0, v1b = 0;
  {
    int gq = qbase + qA;
    double xi = Gx[gq], yi = Gy[gq], zi = Gz[gq], sqi = Gsq[gq];
    if (lane < cntA) {
      j0a = s_cand[qA][lane];
      v0a = 2.0 * (xi * Gx[j0a] + yi * Gy[j0a] + zi * Gz[j0a]) - sqi - Gsq[j0a];
      s_dval[qA][lane] = v0a;
    }
    if (lane + 64 < cntA) {
      j1a = s_cand[qA][lane + 64];
      v1a = 2.0 * (xi * Gx[j1a] + yi * Gy[j1a] + zi * Gz[j1a]) - sqi - Gsq[j1a];
      s_dval[qA][lane + 64] = v1a;
    }
  }
  {
    int gq = qbase + qB;
    double xi = Gx[gq], yi = Gy[gq], zi = Gz[gq], sqi = Gsq[gq];
    if (lane < cntB) {
      j0b = s_cand[qB][lane];
      v0b = 2.0 * (xi * Gx[j0b] + yi * Gy[j0b] + zi * Gz[j0b]) - sqi - Gsq[j0b];
      s_dval[qB][lane] = v0b;
    }
    if (lane + 64 < cntB) {
      j1b = s_cand[qB][lane + 64];
      v1b = 2.0 * (xi * Gx[j1b] + yi * Gy[j1b] + zi * Gz[j1b]) - sqi - Gsq[j1b];
      s_dval[qB][lane + 64] = v1b;
    }
  }
  __syncthreads();
  {
    int r0 = 0, r1 = 0;
    for (int m = 0; m < cntA; ++m) {
      double dv = s_dval[qA][m]; int di = s_cand[qA][m];
      r0 += (dv > v0a) || (dv == v0a && di < j0a);
      r1 += (dv > v1a) || (dv == v1a && di < j1a);
    }
    int gq = qbase + qA;
    if (j0a >= 0 && r0 < KN) knn[gq * KN + r0] = j0a;
    if (j1a >= 0 && r1 < KN) knn[gq * KN + r1] = j1a;
  }
  {
    int r0 = 0, r1 = 0;
    for (int m = 0; m < cntB; ++m) {
      double dv = s_dval[qB][m]; int di = s_cand[qB][m];
      r0 += (dv > v0b) || (dv == v0b && di < j0b);
      r1 += (dv > v1b) || (dv == v1b && di < j1b);
    }
    int gq = qbase + qB;
    if (j0b >= 0 && r0 < KN) knn[gq * KN + r0] = j0b;
    if (j1b >= 0 && r1 < KN) knn[gq * KN + r1] = j1b;
  }
}

// ---------------- attend: per dst node, 16 neighbors, bf16 Q/K/V ---------
__global__ __launch_bounds__(256) void attend_kernel(
    const ushort* __restrict__ Q2, const ushort* __restrict__ K2, const ushort* __restrict__ V2,
    const float4* __restrict__ gpk,
    const int* __restrict__ knn, float* __restrict__ out) {
  const int i    = blockIdx.x;
  const int tid  = threadIdx.x;
  const int wv   = tid >> 6;
  const int lane = tid & 63;

  __shared__ int   s_idx[KN];
  __shared__ float s_w[KN];
  __shared__ float s_se[KN];

  if (tid < KN) s_idx[tid] = knn[i * KN + tid];
  __syncthreads();

  uint4 qa = *(const uint4*)&Q2[(size_t)i * 512 + lane * 8];
  float q0 = bflo(qa.x), q1 = bfhi(qa.x), q2 = bflo(qa.y), q3 = bfhi(qa.y);
  float q4 = bflo(qa.z), q5 = bfhi(qa.z), q6 = bflo(qa.w), q7 = bfhi(qa.w);

  float partial[4];
  #pragma unroll
  for (int s = 0; s < 4; ++s) {
    int src = s_idx[wv * 4 + s];
    uint4 ka = *(const uint4*)&K2[(size_t)src * 512 + lane * 8];
    float acc = q0 * bflo(ka.x);
    acc = fmaf(q1, bfhi(ka.x), acc);
    acc = fmaf(q2, bflo(ka.y), acc);
    acc = fmaf(q3, bfhi(ka.y), acc);
    acc = fmaf(q4, bflo(ka.z), acc);
    acc = fmaf(q5, bfhi(ka.z), acc);
    acc = fmaf(q6, bflo(ka.w), acc);
    acc = fmaf(q7, bfhi(ka.w), acc);
    partial[s] = acc;
  }
  #pragma unroll
  for (int s = 0; s < 4; ++s)
    #pragma unroll
    for (int off = 32; off; off >>= 1) partial[s] += __shfl_down(partial[s], off);

  if (lane == 0) {
    float4 gi = gpk[i];
    #pragma unroll
    for (int s = 0; s < 4; ++s) {
      int e = wv * 4 + s;
      int src = s_idx[e];
      float sc = partial[s] / 22.627417f;
      sc = fminf(fmaxf(sc, -5.f), 5.f);
      float se = expf(sc);
      float4 gs = gpk[src];
      float dx = gi.x - gs.x, dy = gi.y - gs.y, dz = gi.z - gs.z;
      float dd = -sqrtf(fmaf(dx, dx, fmaf(dy, dy, fmaf(dz, dz, 1e-6f))));
      float dc = fminf(fmaxf(dd / 22.627417f, -5.f), 5.f);
      float de = expf(dc);
      s_se[e] = se;
      s_w[e]  = se * de;
    }
  }
  __syncthreads();

  float z = 0.f;
  #pragma unroll
  for (int e = 0; e < KN; ++e) z += s_se[e];

  const int d = tid * 2;
  float a0 = 0.f, a1 = 0.f;
  #pragma unroll
  for (int e = 0; e < KN; ++e) {
    unsigned vv = *(const unsigned*)&V2[(size_t)s_idx[e] * 512 + d];
    a0 = fmaf(s_w[e], bflo(vv), a0);
    a1 = fmaf(s_w[e], bfhi(vv), a1);
  }
  float inv = (z > 0.f) ? (1.f / z) : 1.f;
  float2 o = make_float2(a0 * inv, a1 * inv);
  *(float2*)&out[(size_t)i * 512 + d] = o;
}

extern "C" void kernel_launch(void* const* d_in, const int* in_sizes, int n_in,
                              void* d_out, int out_size, void* d_ws, size_t ws_size,
                              hipStream_t stream) {
  const float* h  = (const float*)d_in[0];
  const float* Wq = (const float*)d_in[1];
  const float* Wk = (const float*)d_in[2];
  const float* Wv = (const float*)d_in[3];
  const float* Wg = (const float*)d_in[4];
  float* out = (float*)d_out;

  char* ws = (char*)d_ws;
  ushort* A2  = (ushort*)(ws);                 // 16 MB
  ushort* Bqk = (ushort*)(ws + (16u << 20));   // 1 MB
  ushort* Bv  = (ushort*)(ws + (17u << 20));   // 1 MB
  ushort* Q2  = (ushort*)(ws + (18u << 20));   // 8 MB
  ushort* K2  = (ushort*)(ws + (26u << 20));   // 8 MB
  ushort* V2  = (ushort*)(ws + (34u << 20));   // 8 MB
  float4* gpk = (float4*)(ws + (42u << 20));   // 128 KB
  double* Gx  = (double*)(ws + (42u << 20) + (1u << 17));
  double* Gy  = Gx + N_NODES;
  double* Gz  = Gy + N_NODES;
  double* Gsq = Gz + N_NODES;
  int*    knn = (int*)(Gsq + N_NODES);         // 512 KB

  hipLaunchKernelGGL(prep_split, dim3(2048 + 768), dim3(256), 0, stream,
                     h, Wg, Wq, Wk, Wv, A2, Bqk, Bv, Gx, Gy, Gz, Gsq, gpk);
  hipLaunchKernelGGL(gemm_qkv, dim3(768), dim3(256), 0, stream,
                     A2, Bqk, Bv, Q2, K2, V2);
  hipLaunchKernelGGL(knn_kernel, dim3(N_NODES / QPB), dim3(256), 0, stream,
                     gpk, Gx, Gy, Gz, Gsq, knn);
  hipLaunchKernelGGL(attend_kernel, dim3(N_NODES), dim3(256), 0, stream,
                     Q2, K2, V2, gpk, knn, out);
}

// Round 9
// 95.044 us; speedup vs baseline: 1.3429x; 1.0895x over previous
//
#include <hip/hip_runtime.h>
#include <hip/hip_bf16.h>
#include <math.h>

#define N_NODES 8192
#define IN_DIM  512
#define OUT_DIM 512
#define KN      16
#define CAP     128
#define QPB     8

typedef __attribute__((ext_vector_type(8))) short bf16x8;
typedef __attribute__((ext_vector_type(4))) float f32x4;
typedef __attribute__((ext_vector_type(2))) float v2f;
typedef __attribute__((ext_vector_type(2))) _Float16 h2;

__device__ __forceinline__ ushort f2bf(float x) {
  __hip_bfloat16 b = __float2bfloat16(x);
  return *reinterpret_cast<ushort*>(&b);
}
__device__ __forceinline__ float bflo(unsigned u) { return __uint_as_float(u << 16); }
__device__ __forceinline__ ushort f2h(float x) {
  _Float16 v = (_Float16)x;
  return __builtin_bit_cast(unsigned short, v);
}
__device__ __forceinline__ v2f fma2(v2f a, v2f b, v2f c) { return __builtin_elementwise_fma(a, b, c); }
__device__ __forceinline__ v2f max2(v2f a, v2f b) { return __builtin_elementwise_max(a, b); }
__device__ __forceinline__ v2f splat2(float x) { v2f r; r.x = x; r.y = x; return r; }

__device__ __forceinline__ float dot2acc(unsigned qu, unsigned ku, float acc) {
#if __has_builtin(__builtin_amdgcn_fdot2)
  return __builtin_amdgcn_fdot2(__builtin_bit_cast(h2, qu), __builtin_bit_cast(h2, ku), acc, false);
#else
  h2 q = __builtin_bit_cast(h2, qu), k = __builtin_bit_cast(h2, ku);
  acc = fmaf((float)q.x, (float)k.x, acc);
  return fmaf((float)q.y, (float)k.y, acc);
#endif
}

#define GLOAD_LDS16(gp, lp)                                                     \
  __builtin_amdgcn_global_load_lds((const __attribute__((address_space(1))) void*)(gp), \
                                   (__attribute__((address_space(3))) void*)(lp), 16, 0, 0)

// ------- fused prep: blocks <2048 do h->A2(bf16 hi) + f64 G; rest split W ----
__global__ __launch_bounds__(256) void prep_split(
    const float* __restrict__ h, const float* __restrict__ Wg,
    const float* __restrict__ Wq, const float* __restrict__ Wk,
    const float* __restrict__ Wv,
    ushort* __restrict__ A2, ushort* __restrict__ B,
    double* __restrict__ Gx, double* __restrict__ Gy,
    double* __restrict__ Gz, double* __restrict__ Gsq,
    float4* __restrict__ gpk) {
  if (blockIdx.x < 2048) {
    const int node = (blockIdx.x * 256 + threadIdx.x) >> 6;
    const int lane = threadIdx.x & 63;
    const int k = lane * 8;
    const float* hr = h + (size_t)node * IN_DIM;

    float4 v0 = *(const float4*)&hr[k];
    float4 v1 = *(const float4*)&hr[k + 4];

    ushort4 hiA = make_ushort4(f2bf(v0.x), f2bf(v0.y), f2bf(v0.z), f2bf(v0.w));
    ushort4 hiB = make_ushort4(f2bf(v1.x), f2bf(v1.y), f2bf(v1.z), f2bf(v1.w));
    size_t base = (size_t)node * 512 + k;
    *(ushort4*)&A2[base]     = hiA;
    *(ushort4*)&A2[base + 4] = hiB;

    float4 w0a = *(const float4*)&Wg[0 * IN_DIM + k];
    float4 w0b = *(const float4*)&Wg[0 * IN_DIM + k + 4];
    float4 w1a = *(const float4*)&Wg[1 * IN_DIM + k];
    float4 w1b = *(const float4*)&Wg[1 * IN_DIM + k + 4];
    float4 w2a = *(const float4*)&Wg[2 * IN_DIM + k];
    float4 w2b = *(const float4*)&Wg[2 * IN_DIM + k + 4];

    double s0 = 0.0, s1 = 0.0, s2 = 0.0;
    s0 += (double)v0.x * w0a.x; s0 += (double)v0.y * w0a.y;
    s0 += (double)v0.z * w0a.z; s0 += (double)v0.w * w0a.w;
    s0 += (double)v1.x * w0b.x; s0 += (double)v1.y * w0b.y;
    s0 += (double)v1.z * w0b.z; s0 += (double)v1.w * w0b.w;
    s1 += (double)v0.x * w1a.x; s1 += (double)v0.y * w1a.y;
    s1 += (double)v0.z * w1a.z; s1 += (double)v0.w * w1a.w;
    s1 += (double)v1.x * w1b.x; s1 += (double)v1.y * w1b.y;
    s1 += (double)v1.z * w1b.z; s1 += (double)v1.w * w1b.w;
    s2 += (double)v0.x * w2a.x; s2 += (double)v0.y * w2a.y;
    s2 += (double)v0.z * w2a.z; s2 += (double)v0.w * w2a.w;
    s2 += (double)v1.x * w2b.x; s2 += (double)v1.y * w2b.y;
    s2 += (double)v1.z * w2b.z; s2 += (double)v1.w * w2b.w;

    #pragma unroll
    for (int off = 32; off; off >>= 1) {
      s0 += __shfl_down(s0, off);
      s1 += __shfl_down(s1, off);
      s2 += __shfl_down(s2, off);
    }
    if (lane == 0) {
      double sq = s0 * s0 + s1 * s1 + s2 * s2;
      Gx[node] = s0; Gy[node] = s1; Gz[node] = s2; Gsq[node] = sq;
      gpk[node] = make_float4((float)s0, (float)s1, (float)s2, -(float)sq);
    }
  } else {
    int i = (blockIdx.x - 2048) * 256 + threadIdx.x;   // 1536*128 float4s
    int n  = i >> 7;
    int kc = (i & 127) << 2;
    const float* W = (n < 512) ? Wq : (n < 1024) ? Wk : Wv;
    int r = n & 511;
    float4 v = *(const float4*)&W[(size_t)r * 512 + kc];
    *(ushort4*)&B[(size_t)n * 512 + kc] =
        make_ushort4(f2bf(v.x), f2bf(v.y), f2bf(v.z), f2bf(v.w));
  }
}

// ---------------- Q/K/V bf16 MFMA GEMM, uniform K=512, f16 output --------
__global__ __launch_bounds__(256) void gemm_qkv(
    const ushort* __restrict__ A2, const ushort* __restrict__ B,
    ushort* __restrict__ Q2, ushort* __restrict__ K2, ushort* __restrict__ V2) {
  __shared__ ushort lA[128 * 32];
  __shared__ ushort lB[128 * 32];
  const int tid = threadIdx.x, w = tid >> 6, lane = tid & 63;
  const int id = blockIdx.x;
  const int sw = (id & 7) * 96 + (id >> 3);   // XCD-contiguous (768%8==0)
  const int bm = sw / 12, bn = sw % 12;
  const int wr = w >> 1, wc = w & 1;

  f32x4 acc[4][4] = {};

  const int   srow = w * 32 + (lane >> 2);
  const int   scol = (lane & 3) * 8;
  const size_t gA0 = (size_t)(bm * 128 + srow) * 512 + scol;
  const size_t gB0 = (size_t)(bn * 128 + srow) * 512 + scol;

  for (int k0 = 0; k0 < 512; k0 += 32) {
    GLOAD_LDS16(&A2[gA0 + k0],            &lA[w * 1024]);
    GLOAD_LDS16(&A2[gA0 + 16 * 512 + k0], &lA[w * 1024 + 512]);
    GLOAD_LDS16(&B[gB0 + k0],             &lB[w * 1024]);
    GLOAD_LDS16(&B[gB0 + 16 * 512 + k0],  &lB[w * 1024 + 512]);
    __syncthreads();

    const int ar = wr * 64 + (lane & 15);
    const int br = wc * 64 + (lane & 15);
    const int kc = (lane >> 4) * 8;
    bf16x8 af[4], bfr[4];
    #pragma unroll
    for (int f = 0; f < 4; ++f) {
      af[f]  = *(const bf16x8*)&lA[(ar + f * 16) * 32 + kc];
      bfr[f] = *(const bf16x8*)&lB[(br + f * 16) * 32 + kc];
    }
    #pragma unroll
    for (int fm = 0; fm < 4; ++fm)
      #pragma unroll
      for (int fn = 0; fn < 4; ++fn)
        acc[fm][fn] = __builtin_amdgcn_mfma_f32_16x16x32_bf16(af[fm], bfr[fn], acc[fm][fn], 0, 0, 0);
    __syncthreads();
  }

  ushort* Cm = (bn < 4) ? Q2 : (bn < 8) ? K2 : V2;
  const int col  = (bn & 3) * 128 + wc * 64 + (lane & 15);
  const int row0 = bm * 128 + wr * 64 + (lane >> 4) * 4;
  #pragma unroll
  for (int fm = 0; fm < 4; ++fm)
    #pragma unroll
    for (int fn = 0; fn < 4; ++fn)
      #pragma unroll
      for (int r = 0; r < 4; ++r)
        Cm[(size_t)(row0 + fm * 16 + r) * 512 + col + fn * 16] = f2h(acc[fm][fn][r]);
}

// ---------------- knn: 8 queries/block, packed-f32 scan, radix-select ----
__global__ __launch_bounds__(256) void knn_kernel(
    const float4* __restrict__ gpk,
    const double* __restrict__ Gx, const double* __restrict__ Gy,
    const double* __restrict__ Gz, const double* __restrict__ Gsq,
    int* __restrict__ knn) {
  const int tid   = threadIdx.x;
  const int w     = tid >> 6;
  const int lane  = tid & 63;
  const int qbase = blockIdx.x * QPB;

  __shared__ float  s_tmax[QPB][256];
  __shared__ int    s_cand[QPB][CAP];
  __shared__ double s_dval[QPB][CAP];
  __shared__ int    s_cnt[QPB];
  __shared__ float  s_T[QPB];

  float q2x[QPB], q2y[QPB], q2z[QPB];
  v2f tm2[QPB];
  #pragma unroll
  for (int s = 0; s < QPB; ++s) {
    float4 qv = gpk[qbase + s];
    q2x[s] = 2.f * qv.x; q2y[s] = 2.f * qv.y; q2z[s] = 2.f * qv.z;
    tm2[s] = splat2(-1e30f);
  }
  if (tid < QPB) s_cnt[tid] = 0;

  // Phase A: packed branchless max scan with register prefetch
  {
    float4 c0 = gpk[tid];
    float4 c1 = gpk[tid + 256];
    for (int i = 0; i < 16; ++i) {
      int nx = ((i + 1) & 15) * 512;
      float4 n0 = gpk[tid + nx];
      float4 n1 = gpk[tid + nx + 256];
      v2f cx, cy, cz, cw;
      cx.x = c0.x; cx.y = c1.x;
      cy.x = c0.y; cy.y = c1.y;
      cz.x = c0.z; cz.y = c1.z;
      cw.x = c0.w; cw.y = c1.w;
      #pragma unroll
      for (int s = 0; s < QPB; ++s) {
        v2f v = fma2(splat2(q2x[s]), cx,
                 fma2(splat2(q2y[s]), cy,
                  fma2(splat2(q2z[s]), cz, cw)));
        tm2[s] = max2(tm2[s], v);
      }
      c0 = n0; c1 = n1;
    }
  }
  #pragma unroll
  for (int s = 0; s < QPB; ++s) s_tmax[s][tid] = fmaxf(tm2[s].x, tm2[s].y);
  __syncthreads();

  // Phase B: exact 16th-of-64 via radix select on monotone float->uint map
  #pragma unroll
  for (int qq = 0; qq < 2; ++qq) {
    int q = w * 2 + qq;
    float v = fmaxf(fmaxf(s_tmax[q][lane], s_tmax[q][lane + 64]),
                    fmaxf(s_tmax[q][lane + 128], s_tmax[q][lane + 192]));
    unsigned b = __float_as_uint(v);
    unsigned u = b ^ ((unsigned)((int)b >> 31) | 0x80000000u);
    unsigned thr = 0;
    for (int bit = 31; bit >= 0; --bit) {
      unsigned cand = thr | (1u << bit);
      unsigned long long m = __ballot(u >= cand);
      if (__popcll(m) >= KN) thr = cand;
    }
    unsigned tb = (thr & 0x80000000u) ? (thr ^ 0x80000000u) : ~thr;
    if (lane == 0) s_T[q] = __uint_as_float(tb);
  }
  __syncthreads();

  // Phase C: packed rescan (identical FMA chain), collect candidates >= T
  float Ts[QPB];
  #pragma unroll
  for (int s = 0; s < QPB; ++s) Ts[s] = s_T[s];
  {
    float4 c0 = gpk[tid];
    float4 c1 = gpk[tid + 256];
    for (int i = 0; i < 16; ++i) {
      int nx = ((i + 1) & 15) * 512;
      float4 n0 = gpk[tid + nx];
      float4 n1 = gpk[tid + nx + 256];
      int j0 = tid + i * 512, j1 = j0 + 256;
      v2f cx, cy, cz, cw;
      cx.x = c0.x; cx.y = c1.x;
      cy.x = c0.y; cy.y = c1.y;
      cz.x = c0.z; cz.y = c1.z;
      cw.x = c0.w; cw.y = c1.w;
      #pragma unroll
      for (int s = 0; s < QPB; ++s) {
        v2f v = fma2(splat2(q2x[s]), cx,
                 fma2(splat2(q2y[s]), cy,
                  fma2(splat2(q2z[s]), cz, cw)));
        if (v.x >= Ts[s]) { int p = atomicAdd(&s_cnt[s], 1); if (p < CAP) s_cand[s][p] = j0; }
        if (v.y >= Ts[s]) { int p = atomicAdd(&s_cnt[s], 1); if (p < CAP) s_cand[s][p] = j1; }
      }
      c0 = n0; c1 = n1;
    }
  }
  __syncthreads();

  // Phase D: exact f64 scores, rank-by-counting
  const int qA = w * 2, qB = qA + 1;
  const int cntA = min(s_cnt[qA], CAP);
  const int cntB = min(s_cnt[qB], CAP);
  int j0a = -1, j1a = -1, j0b = -1, j1b = -1;
  double v0a = 0, v1a = 0, v0b = 0, v1b = 0;
  {
    int gq = qbase + qA;
    double xi = Gx[gq], yi = Gy[gq], zi = Gz[gq], sqi = Gsq[gq];
    if (lane < cntA) {
      j0a = s_cand[qA][lane];
      v0a = 2.0 * (xi * Gx[j0a] + yi * Gy[j0a] + zi * Gz[j0a]) - sqi - Gsq[j0a];
      s_dval[qA][lane] = v0a;
    }
    if (lane + 64 < cntA) {
      j1a = s_cand[qA][lane + 64];
      v1a = 2.0 * (xi * Gx[j1a] + yi * Gy[j1a] + zi * Gz[j1a]) - sqi - Gsq[j1a];
      s_dval[qA][lane + 64] = v1a;
    }
  }
  {
    int gq = qbase + qB;
    double xi = Gx[gq], yi = Gy[gq], zi = Gz[gq], sqi = Gsq[gq];
    if (lane < cntB) {
      j0b = s_cand[qB][lane];
      v0b = 2.0 * (xi * Gx[j0b] + yi * Gy[j0b] + zi * Gz[j0b]) - sqi - Gsq[j0b];
      s_dval[qB][lane] = v0b;
    }
    if (lane + 64 < cntB) {
      j1b = s_cand[qB][lane + 64];
      v1b = 2.0 * (xi * Gx[j1b] + yi * Gy[j1b] + zi * Gz[j1b]) - sqi - Gsq[j1b];
      s_dval[qB][lane + 64] = v1b;
    }
  }
  __syncthreads();
  {
    int r0 = 0, r1 = 0;
    for (int m = 0; m < cntA; ++m) {
      double dv = s_dval[qA][m]; int di = s_cand[qA][m];
      r0 += (dv > v0a) || (dv == v0a && di < j0a);
      r1 += (dv > v1a) || (dv == v1a && di < j1a);
    }
    int gq = qbase + qA;
    if (j0a >= 0 && r0 < KN) knn[gq * KN + r0] = j0a;
    if (j1a >= 0 && r1 < KN) knn[gq * KN + r1] = j1a;
  }
  {
    int r0 = 0, r1 = 0;
    for (int m = 0; m < cntB; ++m) {
      double dv = s_dval[qB][m]; int di = s_cand[qB][m];
      r0 += (dv > v0b) || (dv == v0b && di < j0b);
      r1 += (dv > v1b) || (dv == v1b && di < j1b);
    }
    int gq = qbase + qB;
    if (j0b >= 0 && r0 < KN) knn[gq * KN + r0] = j0b;
    if (j1b >= 0 && r1 < KN) knn[gq * KN + r1] = j1b;
  }
}

// ---------------- attend: per dst node, 16 neighbors, f16 Q/K/V ----------
__global__ __launch_bounds__(256) void attend_kernel(
    const ushort* __restrict__ Q2, const ushort* __restrict__ K2, const ushort* __restrict__ V2,
    const float4* __restrict__ gpk,
    const int* __restrict__ knn, float* __restrict__ out) {
  const int i    = blockIdx.x;
  const int tid  = threadIdx.x;
  const int wv   = tid >> 6;
  const int lane = tid & 63;

  __shared__ int   s_idx[KN];
  __shared__ float s_w[KN];
  __shared__ float s_se[KN];

  if (tid < KN) s_idx[tid] = knn[i * KN + tid];
  __syncthreads();

  uint4 qa = *(const uint4*)&Q2[(size_t)i * 512 + lane * 8];

  float partial[4];
  #pragma unroll
  for (int s = 0; s < 4; ++s) {
    int src = s_idx[wv * 4 + s];
    uint4 ka = *(const uint4*)&K2[(size_t)src * 512 + lane * 8];
    float acc = dot2acc(qa.x, ka.x, 0.f);
    acc = dot2acc(qa.y, ka.y, acc);
    acc = dot2acc(qa.z, ka.z, acc);
    acc = dot2acc(qa.w, ka.w, acc);
    partial[s] = acc;
  }
  #pragma unroll
  for (int s = 0; s < 4; ++s)
    #pragma unroll
    for (int off = 32; off; off >>= 1) partial[s] += __shfl_down(partial[s], off);

  if (lane == 0) {
    float4 gi = gpk[i];
    #pragma unroll
    for (int s = 0; s < 4; ++s) {
      int e = wv * 4 + s;
      int src = s_idx[e];
      float sc = partial[s] / 22.627417f;
      sc = fminf(fmaxf(sc, -5.f), 5.f);
      float se = expf(sc);
      float4 gs = gpk[src];
      float dx = gi.x - gs.x, dy = gi.y - gs.y, dz = gi.z - gs.z;
      float dd = -sqrtf(fmaf(dx, dx, fmaf(dy, dy, fmaf(dz, dz, 1e-6f))));
      float dc = fminf(fmaxf(dd / 22.627417f, -5.f), 5.f);
      float de = expf(dc);
      s_se[e] = se;
      s_w[e]  = se * de;
    }
  }
  __syncthreads();

  float z = 0.f;
  #pragma unroll
  for (int e = 0; e < KN; ++e) z += s_se[e];

  const int d = tid * 2;
  float a0 = 0.f, a1 = 0.f;
  #pragma unroll
  for (int e = 0; e < KN; ++e) {
    unsigned vv = *(const unsigned*)&V2[(size_t)s_idx[e] * 512 + d];
    h2 vh = __builtin_bit_cast(h2, vv);
    a0 = fmaf(s_w[e], (float)vh.x, a0);
    a1 = fmaf(s_w[e], (float)vh.y, a1);
  }
  float inv = (z > 0.f) ? (1.f / z) : 1.f;
  float2 o = make_float2(a0 * inv, a1 * inv);
  *(float2*)&out[(size_t)i * 512 + d] = o;
}

extern "C" void kernel_launch(void* const* d_in, const int* in_sizes, int n_in,
                              void* d_out, int out_size, void* d_ws, size_t ws_size,
                              hipStream_t stream) {
  const float* h  = (const float*)d_in[0];
  const float* Wq = (const float*)d_in[1];
  const float* Wk = (const float*)d_in[2];
  const float* Wv = (const float*)d_in[3];
  const float* Wg = (const float*)d_in[4];
  float* out = (float*)d_out;

  char* ws = (char*)d_ws;
  ushort* A2  = (ushort*)(ws);                 // 8 MB
  ushort* B   = (ushort*)(ws + (8u << 20));    // 1.5 MB
  ushort* Q2  = (ushort*)(ws + (10u << 20));   // 8 MB (f16)
  ushort* K2  = (ushort*)(ws + (18u << 20));   // 8 MB (f16)
  ushort* V2  = (ushort*)(ws + (26u << 20));   // 8 MB (f16)
  float4* gpk = (float4*)(ws + (34u << 20));   // 128 KB
  double* Gx  = (double*)(ws + (34u << 20) + (1u << 17));
  double* Gy  = Gx + N_NODES;
  double* Gz  = Gy + N_NODES;
  double* Gsq = Gz + N_NODES;
  int*    knn = (int*)(Gsq + N_NODES);         // 512 KB

  hipLaunchKernelGGL(prep_split, dim3(2048 + 768), dim3(256), 0, stream,
                     h, Wg, Wq, Wk, Wv, A2, B, Gx, Gy, Gz, Gsq, gpk);
  hipLaunchKernelGGL(gemm_qkv, dim3(768), dim3(256), 0, stream,
                     A2, B, Q2, K2, V2);
  hipLaunchKernelGGL(knn_kernel, dim3(N_NODES / QPB), dim3(256), 0, stream,
                     gpk, Gx, Gy, Gz, Gsq, knn);
  hipLaunchKernelGGL(attend_kernel, dim3(N_NODES), dim3(256), 0, stream,
                     Q2, K2, V2, gpk, knn, out);
}